// Round 13
// baseline (135.369 us; speedup 1.0000x reference)
//
#include <hip/hip_runtime.h>
#include <hip/hip_bf16.h>
#include <hip/hip_fp16.h>

typedef __attribute__((ext_vector_type(4))) float f32x4;
typedef __attribute__((ext_vector_type(8))) _Float16 f16x8;
typedef __attribute__((ext_vector_type(8))) unsigned short u16x8;

__device__ __forceinline__ unsigned short f2h(float f) {
    _Float16 h = (_Float16)f;
    return __builtin_bit_cast(unsigned short, h);
}

#define GLOAD_LDS16(gp, lp) __builtin_amdgcn_global_load_lds( \
    (const __attribute__((address_space(1))) void*)(gp), \
    (__attribute__((address_space(3))) void*)(lp), 16, 0, 0)
#define PRIO1() __builtin_amdgcn_s_setprio(1)
#define PRIO0() __builtin_amdgcn_s_setprio(0)

// ---------------- fp32 -> fp16 elementwise convert (vectorized) ----------------
__global__ void cvt_kernel(const float* __restrict__ in, ushort* __restrict__ out, int n4) {
    int stride = gridDim.x * blockDim.x;
    for (int i = blockIdx.x * blockDim.x + threadIdx.x; i < n4; i += stride) {
        float4 v = ((const float4*)in)[i];
        ushort4 o;
        o.x = f2h(v.x); o.y = f2h(v.y); o.z = f2h(v.z); o.w = f2h(v.w);
        ((ushort4*)out)[i] = o;
    }
}

// ---------------- transpose + convert Wk/Wv (for the KV projection GEMM) ----------------
__global__ void transpose_cvt2(const float* __restrict__ Wk, const float* __restrict__ Wv,
                               ushort* __restrict__ WkvT) {
    __shared__ float tile[32][33];
    const int z = blockIdx.z;
    const float* src = z ? Wv : Wk;
    ushort* dst = WkvT + (size_t)z * 640 * 768;
    const int R = 768, C = 640;
    int tx = threadIdx.x, ty = threadIdx.y;
    int c = blockIdx.x * 32 + tx;
    int r0 = blockIdx.y * 32;
#pragma unroll
    for (int i = ty; i < 32; i += 8) {
        int r = r0 + i;
        tile[i][tx] = (r < R && c < C) ? src[(size_t)r * C + c] : 0.f;
    }
    __syncthreads();
    int rr = r0 + tx;
    int c0 = blockIdx.x * 32;
#pragma unroll
    for (int i = ty; i < 32; i += 8) {
        int cc = c0 + i;
        if (cc < C && rr < R) dst[(size_t)cc * R + rr] = f2h(tile[tx][i]);
    }
}

// ---------------- pack W (fp32 [640 k][640 n]) into fragment-linear f16 ----------------
__global__ void pack_wfrag(const float* __restrict__ W, ushort* __restrict__ WF) {
    int g = blockIdx.x * 256 + threadIdx.x;   // 0 .. 51199
    if (g >= 51200) return;
    int lane = g & 63;
    int fi = (g >> 6) % 10;
    int kt = ((g >> 6) / 10) % 10;
    int h  = (g >> 6) / 100;
    int ni = fi >> 1, kk = fi & 1;
    int n  = h * 80 + ni * 16 + (lane & 15);
    int k0 = kt * 64 + kk * 32 + (lane >> 4) * 8;
    u16x8 o;
#pragma unroll
    for (int e = 0; e < 8; ++e) o[e] = f2h(W[(size_t)(k0 + e) * 640 + n]);
    *(u16x8*)&WF[(size_t)g * 8] = o;
}

// ---------------- pack K,V fragments from KVb ----------------
__global__ void pack_kvfrag(const ushort* __restrict__ KVb,
                            ushort* __restrict__ KF, ushort* __restrict__ VF) {
    int g = blockIdx.x * 256 + threadIdx.x;   // 0 .. 61439
    if (g >= 61440) return;
    int lane = g & 63;
    int fi = (g >> 6) % 15;
    int bh = (g >> 6) / 15;
    int b = bh >> 3, h = bh & 7;
    int ni = fi / 3, kk = fi % 3;
    int l15 = lane & 15, lhi = lane >> 4;
    int sr = ni * 16 + l15; if (sr > 76) sr = 76;
    int d0 = kk * 32 + lhi * 8;
    u16x8 ko, vo;
#pragma unroll
    for (int e = 0; e < 8; ++e)
        ko[e] = KVb[((size_t)b * 77 + sr) * 1280 + h * 80 + d0 + e];
    int dv = ni * 16 + l15;            // < 80 always
    int s0 = kk * 32 + lhi * 8;
#pragma unroll
    for (int e = 0; e < 8; ++e) {
        int s = s0 + e;
        vo[e] = (s < 77) ? KVb[((size_t)b * 77 + s) * 1280 + 640 + h * 80 + dv] : (ushort)0;
    }
    *(u16x8*)&KF[(size_t)g * 8] = ko;
    *(u16x8*)&VF[(size_t)g * 8] = vo;
}

// ---------------- 128x128 GEMM (for the tiny KV projection) ----------------
template<int OUT_F16, int HAS_BIAS>
__global__ __launch_bounds__(256) void gemm_bt(
    const ushort* __restrict__ A, const ushort* __restrict__ Bt,
    void* __restrict__ C, const float* __restrict__ bias,
    int M, int N, int K)
{
    __shared__ ushort As[128 * 64];
    __shared__ ushort Bs[128 * 64];
    const int tid = threadIdx.x;
    const int lane = tid & 63;
    const int w = tid >> 6;
    const int wr = (w >> 1) * 64, wc = (w & 1) * 64;
    const int m0 = blockIdx.x * 128, n0 = blockIdx.y * 128;
    const int l15 = lane & 15, lhi = lane >> 4;

    f32x4 acc[4][4] = {};

    for (int k0 = 0; k0 < K; k0 += 64) {
        __syncthreads();
#pragma unroll
        for (int i = 0; i < 4; ++i) {
            int c = i * 256 + tid;
            int m = m0 + (c >> 3);
            if (m > M - 1) m = M - 1;
            GLOAD_LDS16(A + (size_t)m * K + k0 + (c & 7) * 8, &As[c * 8]);
        }
#pragma unroll
        for (int i = 0; i < 4; ++i) {
            int c = i * 256 + tid;
            GLOAD_LDS16(Bt + (size_t)(n0 + (c >> 3)) * K + k0 + (c & 7) * 8, &Bs[c * 8]);
        }
        __syncthreads();
#pragma unroll
        for (int kk = 0; kk < 2; ++kk) {
            f16x8 af[4], bfr[4];
#pragma unroll
            for (int mi = 0; mi < 4; ++mi)
                af[mi] = *(const f16x8*)&As[(wr + mi * 16 + l15) * 64 + kk * 32 + lhi * 8];
#pragma unroll
            for (int ni = 0; ni < 4; ++ni)
                bfr[ni] = *(const f16x8*)&Bs[(wc + ni * 16 + l15) * 64 + kk * 32 + lhi * 8];
#pragma unroll
            for (int mi = 0; mi < 4; ++mi)
#pragma unroll
                for (int ni = 0; ni < 4; ++ni)
                    acc[mi][ni] = __builtin_amdgcn_mfma_f32_16x16x32_f16(
                        af[mi], bfr[ni], acc[mi][ni], 0, 0, 0);
        }
    }

#pragma unroll
    for (int mi = 0; mi < 4; ++mi)
#pragma unroll
        for (int ni = 0; ni < 4; ++ni)
#pragma unroll
            for (int r = 0; r < 4; ++r) {
                int row = m0 + wr + mi * 16 + lhi * 4 + r;
                int col = n0 + wc + ni * 16 + l15;
                if (row < M) {
                    float v = acc[mi][ni][r];
                    if (HAS_BIAS) v += bias[col];
                    if (OUT_F16) ((ushort*)C)[(size_t)row * N + col] = f2h(v);
                    else         ((float*)C)[(size_t)row * N + col] = v;
                }
            }
}

// ================= fused: tokens->Q-proj->attention->O-proj->out =================
// R13: decouple wave-geometry from block-geometry.
//   1024 threads = 16 waves; wave w: head h = w&7, rowhalf rh = w>>3 (32 rows each).
//   Block covers 64 T-rows x all 8 heads -> W-frag L2 amortization = R8 (512 blocks).
//   Per-wave regs: acc[2][5] = 40 + ~80 VGPR ~= 120 total <= 128 -> 4 waves/SIMD
//   (16 waves/CU) — the R4-R12 ledger says 2 waves/SIMD was the latency wall; R10
//   proved acc[2][5] reaches 3-4 waves/SIMD but paid 2x W-traffic via 32-row BLOCKS.
//   This config gets both. launch_bounds(1024,1): cap = 512/(4 waves/SIMD) = 128.
// LDS 80 KiB sequential aliasing:
//   token dbuf [2][64][64] @0/4096 ushorts (16 KB; stagers = tid<512)
//   Q/P per-wave [32][80] @ w*2560 (80 KB; after toks dead)
//   ctxall [64][640] swz @0 (80 KB; after PV)
__global__ __launch_bounds__(1024, 1) void fused_attn(
    const float* __restrict__ tokens, const ushort* __restrict__ WqF,
    const ushort* __restrict__ KF, const ushort* __restrict__ VF,
    const ushort* __restrict__ WoF, const float* __restrict__ bo,
    float* __restrict__ out)
{
    __shared__ __align__(16) ushort lds[40960];   // 80 KiB
    const int tid = threadIdx.x;
    const int lane = tid & 63;
    const int w = tid >> 6;          // 0..15
    const int h = w & 7;
    const int rh = w >> 3;           // 0,1
    const int l15 = lane & 15, lhi = lane >> 4;
    const int tt = blockIdx.x, b = blockIdx.y;
    const size_t rowbase = (size_t)b * 4096 + (size_t)tt * 64;

    const ushort* WqFb = WqF + (size_t)h * 10 * 5120;
    const ushort* WoFb = WoF + (size_t)h * 10 * 5120;
    const ushort* KFb  = KF + (size_t)(b * 8 + h) * 15 * 512;
    const ushort* VFb  = VF + (size_t)(b * 8 + h) * 15 * 512;

    // staging (threads 0..511): entry e=tid: row=e>>3 (0..63), 16B slot=e&7
    const bool stager = tid < 512;
    const int rs = (tid & 511) >> 3;
    const int ss = tid & 7;
    const int ds = rs * 64 + (ss ^ (rs & 7)) * 8;   // swizzled dest (ushorts)

#define STAGE_LOAD(C, A0, B0) do { \
    if (stager) { \
        const float* p_ = tokens + (rowbase + rs) * 640 + (C) * 64 + ss * 8; \
        A0 = ((const float4*)p_)[0]; B0 = ((const float4*)p_)[1]; \
    } \
} while (0)
#define STAGE_WRITE(BUF, A0, B0) do { \
    if (stager) { \
        u16x8 o_; \
        o_[0]=f2h(A0.x); o_[1]=f2h(A0.y); o_[2]=f2h(A0.z); o_[3]=f2h(A0.w); \
        o_[4]=f2h(B0.x); o_[5]=f2h(B0.y); o_[6]=f2h(B0.z); o_[7]=f2h(B0.w); \
        *(u16x8*)&lds[(BUF) * 4096 + ds] = o_; \
    } \
} while (0)

    // ---- prologue: stage chunk 0 into buf0 ----
    {
        float4 a0, b0;
        STAGE_LOAD(0, a0, b0);
        STAGE_WRITE(0, a0, b0);
    }
    f16x8 PE[5], PO[5];
#pragma unroll
    for (int f = 0; f < 5; ++f)
        PE[f] = *(const f16x8*)(WqFb + (f * 2) * 512 + lane * 8);
    __syncthreads();

    f32x4 acc[2][5];
#define ZACC() do { \
    _Pragma("unroll") for (int i_ = 0; i_ < 2; ++i_) \
    _Pragma("unroll") for (int j_ = 0; j_ < 5; ++j_) \
        acc[i_][j_] = (f32x4){0.f, 0.f, 0.f, 0.f}; \
} while (0)

// one kk-half: optional 5-frag B prefetch; 2 A-frags read singly
#define MHALF(PC, PN, WB, CURB, RSTR, SBASE, KK, NKT, NKK, DOPF) do { \
    if (DOPF) { \
        _Pragma("unroll") for (int f = 0; f < 5; ++f) \
            (PN)[f] = *(const f16x8*)((WB) + (size_t)(NKT) * 5120 + (f * 2 + (NKK)) * 512 + lane * 8); \
    } \
    PRIO1(); \
    _Pragma("unroll") for (int mi = 0; mi < 2; ++mi) { \
        int row_ = rh * 32 + mi * 16 + l15; \
        f16x8 a_ = *(const f16x8*)&lds[(CURB) + row_ * (RSTR) + ((SBASE) + (((KK) * 4 + lhi) ^ (row_ & 7))) * 8]; \
        _Pragma("unroll") for (int ni = 0; ni < 5; ++ni) \
            acc[mi][ni] = __builtin_amdgcn_mfma_f32_16x16x32_f16(a_, (PC)[ni], acc[mi][ni], 0, 0, 0); \
    } \
    PRIO0(); \
} while (0)

    // ---- Q projection: acc = toks(64x640) @ Wq[:, h*80..+80]  (rows rh*32..+32) ----
    ZACC();
    for (int kt = 0; kt < 10; ++kt) {
        const int curb = (kt & 1) * 4096;
        float4 a0, b0;
        if (kt < 9) STAGE_LOAD(kt + 1, a0, b0);
        MHALF(PE, PO, WqFb, curb, 64, 0, 0, kt, 1, 1);
        MHALF(PO, PE, WqFb, curb, 64, 0, 1, kt + 1, 0, kt < 9);
        if (kt < 9) STAGE_WRITE((kt + 1) & 1, a0, b0);
        __syncthreads();
    }

    // ---- write Q f16 into per-wave [32][80] region (aliases token dbuf) ----
    const int qoff = w * 2560;
#pragma unroll
    for (int mi = 0; mi < 2; ++mi)
#pragma unroll
        for (int ni = 0; ni < 5; ++ni)
#pragma unroll
            for (int r = 0; r < 4; ++r)
                lds[qoff + (mi*16 + lhi*4 + r)*80 + ni*16 + l15] = f2h(acc[mi][ni][r]);
    __builtin_amdgcn_sched_barrier(0);

    const f16x8 zf = {};
    // ---- S = Q K^T (packed K frags, kk-level prefetch) ----
#define ATT_KK(PC, PN, FB, KK, NKK, DOPF) do { \
    if (DOPF) { \
        _Pragma("unroll") for (int f = 0; f < 5; ++f) \
            (PN)[f] = *(const f16x8*)((FB) + (f * 3 + (NKK)) * 512 + lane * 8); \
    } \
    const int kcol = ((KK) < 2) ? ((KK)*32 + lhi*8) : (64 + (lhi & 1)*8); \
    PRIO1(); \
    _Pragma("unroll") for (int mi = 0; mi < 2; ++mi) { \
        f16x8 aq_ = *(const f16x8*)&lds[qoff + (mi*16 + l15)*80 + kcol]; \
        if ((KK) == 2 && lhi >= 2) aq_ = zf; \
        _Pragma("unroll") for (int ni = 0; ni < 5; ++ni) \
            acc[mi][ni] = __builtin_amdgcn_mfma_f32_16x16x32_f16(aq_, (PC)[ni], acc[mi][ni], 0, 0, 0); \
    } \
    PRIO0(); \
} while (0)

    ZACC();
#pragma unroll
    for (int f = 0; f < 5; ++f)
        PE[f] = *(const f16x8*)(KFb + (f * 3) * 512 + lane * 8);
    ATT_KK(PE, PO, KFb, 0, 1, 1);
    ATT_KK(PO, PE, KFb, 1, 2, 1);
    ATT_KK(PE, PO, KFb, 2, 0, 0);
    __builtin_amdgcn_sched_barrier(0);

    // ---- softmax over s (77 valid), P f16 back into the same region ----
    const float sc = 0.11180339887498949f;   // 1/sqrt(80)
#pragma unroll
    for (int mi = 0; mi < 2; ++mi)
#pragma unroll
        for (int r = 0; r < 4; ++r) {
            float v0 = acc[mi][0][r]*sc, v1 = acc[mi][1][r]*sc, v2 = acc[mi][2][r]*sc,
                  v3 = acc[mi][3][r]*sc, v4 = acc[mi][4][r]*sc;
            bool ok4 = l15 < 13;             // col 64+l15 < 77
            float mx = fmaxf(fmaxf(v0, v1), fmaxf(v2, v3));
            if (ok4) mx = fmaxf(mx, v4);
#pragma unroll
            for (int off = 1; off < 16; off <<= 1) mx = fmaxf(mx, __shfl_xor(mx, off, 16));
            float p0 = __expf(v0-mx), p1 = __expf(v1-mx), p2 = __expf(v2-mx), p3 = __expf(v3-mx);
            float p4 = ok4 ? __expf(v4-mx) : 0.f;
            float sm = p0+p1+p2+p3+p4;
#pragma unroll
            for (int off = 1; off < 16; off <<= 1) sm += __shfl_xor(sm, off, 16);
            float inv = 1.f / sm;
            int row = mi*16 + lhi*4 + r;
            lds[qoff + row*80 + 0*16 + l15] = f2h(p0*inv);
            lds[qoff + row*80 + 1*16 + l15] = f2h(p1*inv);
            lds[qoff + row*80 + 2*16 + l15] = f2h(p2*inv);
            lds[qoff + row*80 + 3*16 + l15] = f2h(p3*inv);
            lds[qoff + row*80 + 4*16 + l15] = f2h(p4*inv);
        }
    __builtin_amdgcn_sched_barrier(0);

    // ---- O = P V (packed V frags; s>=77 cols are true zeros) ----
    ZACC();
#pragma unroll
    for (int f = 0; f < 5; ++f)
        PE[f] = *(const f16x8*)(VFb + (f * 3) * 512 + lane * 8);
    ATT_KK(PE, PO, VFb, 0, 1, 1);
    ATT_KK(PO, PE, VFb, 1, 2, 1);
    ATT_KK(PE, PO, VFb, 2, 0, 0);
#undef ATT_KK
    __syncthreads();                      // Q/P regions dead everywhere

    // ---- ctxall [64][640] swizzled = concat of heads ----
#pragma unroll
    for (int mi = 0; mi < 2; ++mi)
#pragma unroll
        for (int ni = 0; ni < 5; ++ni)
#pragma unroll
            for (int r = 0; r < 4; ++r) {
                int row = rh*32 + mi*16 + lhi*4 + r;
                int col = h*80 + ni*16 + l15;
                int slot = col >> 3;
                int phys = (slot & ~7) | ((slot ^ row) & 7);
                lds[row*640 + phys*8 + (col & 7)] = f2h(acc[mi][ni][r]);
            }
    __syncthreads();                      // ctxall ready

    // ---- O projection (barrier-free): out = ctxall @ Wo + bo ----
    ZACC();
#pragma unroll
    for (int f = 0; f < 5; ++f)
        PE[f] = *(const f16x8*)(WoFb + (f * 2) * 512 + lane * 8);
    for (int kt = 0; kt < 10; ++kt) {
        MHALF(PE, PO, WoFb, 0, 640, kt * 8, 0, kt, 1, 1);
        MHALF(PO, PE, WoFb, 0, 640, kt * 8, 1, kt + 1, 0, kt < 9);
    }
#undef MHALF
#undef ZACC

    // ---- epilogue: f32 out + bias ----
#pragma unroll
    for (int ni = 0; ni < 5; ++ni) {
        int col = h*80 + ni*16 + l15;
        float bvl = bo[col];
#pragma unroll
        for (int mi = 0; mi < 2; ++mi)
#pragma unroll
            for (int r = 0; r < 4; ++r)
                out[(rowbase + rh*32 + mi*16 + lhi*4 + r) * 640 + col] = acc[mi][ni][r] + bvl;
    }
#undef STAGE_LOAD
#undef STAGE_WRITE
}

extern "C" void kernel_launch(void* const* d_in, const int* in_sizes, int n_in,
                              void* d_out, int out_size, void* d_ws, size_t ws_size,
                              hipStream_t stream) {
    (void)in_sizes; (void)n_in; (void)out_size; (void)ws_size;
    const float* tokens  = (const float*)d_in[0];
    const float* context = (const float*)d_in[1];
    const float* Wq = (const float*)d_in[2];
    const float* Wk = (const float*)d_in[3];
    const float* Wv = (const float*)d_in[4];
    const float* Wo = (const float*)d_in[5];
    const float* bo = (const float*)d_in[6];
    float* out = (float*)d_out;

    ushort* ws   = (ushort*)d_ws;
    ushort* ctx16 = ws;                                   // 616*768
    ushort* WkvT = ctx16 + (size_t)616 * 768;             // 1280*768
    ushort* KVb  = WkvT + (size_t)1280 * 768;             // 616*1280
    ushort* WqF  = KVb  + (size_t)616 * 1280;             // 640*640
    ushort* WoF  = WqF  + (size_t)640 * 640;              // 640*640
    ushort* KF   = WoF  + (size_t)640 * 640;              // 61440*8
    ushort* VF   = KF   + (size_t)61440 * 8;              // 61440*8

    cvt_kernel<<<462, 256, 0, stream>>>(context, ctx16, 616 * 768 / 4);
    transpose_cvt2<<<dim3(20, 24, 2), dim3(32, 8), 0, stream>>>(Wk, Wv, WkvT);
    pack_wfrag<<<200, 256, 0, stream>>>(Wq, WqF);
    pack_wfrag<<<200, 256, 0, stream>>>(Wo, WoF);
    gemm_bt<1, 0><<<dim3(5, 10), 256, 0, stream>>>(ctx16, WkvT, KVb, nullptr, 616, 1280, 768);
    pack_kvfrag<<<240, 256, 0, stream>>>(KVb, KF, VF);
    fused_attn<<<dim3(64, 8), 1024, 0, stream>>>(tokens, WqF, KF, VF, WoF, bo, out);
}

// Round 14
// 127.218 us; speedup vs baseline: 1.0641x; 1.0641x over previous
//
#include <hip/hip_runtime.h>
#include <hip/hip_bf16.h>
#include <hip/hip_fp16.h>

typedef __attribute__((ext_vector_type(4))) float f32x4;
typedef __attribute__((ext_vector_type(8))) _Float16 f16x8;
typedef __attribute__((ext_vector_type(8))) unsigned short u16x8;

__device__ __forceinline__ unsigned short f2h(float f) {
    _Float16 h = (_Float16)f;
    return __builtin_bit_cast(unsigned short, h);
}

#define GLOAD_LDS16(gp, lp) __builtin_amdgcn_global_load_lds( \
    (const __attribute__((address_space(1))) void*)(gp), \
    (__attribute__((address_space(3))) void*)(lp), 16, 0, 0)
#define PRIO1() __builtin_amdgcn_s_setprio(1)
#define PRIO0() __builtin_amdgcn_s_setprio(0)
// counted vmcnt with literal, plus sched fence (rule #18 analog)
#define WAITVM(LIT) do { asm volatile("s_waitcnt vmcnt(" #LIT ")" ::: "memory"); \
                         __builtin_amdgcn_sched_barrier(0); } while (0)

// ---------------- fp32 -> fp16 elementwise convert (vectorized) ----------------
__global__ void cvt_kernel(const float* __restrict__ in, ushort* __restrict__ out, int n4) {
    int stride = gridDim.x * blockDim.x;
    for (int i = blockIdx.x * blockDim.x + threadIdx.x; i < n4; i += stride) {
        float4 v = ((const float4*)in)[i];
        ushort4 o;
        o.x = f2h(v.x); o.y = f2h(v.y); o.z = f2h(v.z); o.w = f2h(v.w);
        ((ushort4*)out)[i] = o;
    }
}

// ---------------- transpose + convert Wk/Wv (for the KV projection GEMM) ----------------
__global__ void transpose_cvt2(const float* __restrict__ Wk, const float* __restrict__ Wv,
                               ushort* __restrict__ WkvT) {
    __shared__ float tile[32][33];
    const int z = blockIdx.z;
    const float* src = z ? Wv : Wk;
    ushort* dst = WkvT + (size_t)z * 640 * 768;
    const int R = 768, C = 640;
    int tx = threadIdx.x, ty = threadIdx.y;
    int c = blockIdx.x * 32 + tx;
    int r0 = blockIdx.y * 32;
#pragma unroll
    for (int i = ty; i < 32; i += 8) {
        int r = r0 + i;
        tile[i][tx] = (r < R && c < C) ? src[(size_t)r * C + c] : 0.f;
    }
    __syncthreads();
    int rr = r0 + tx;
    int c0 = blockIdx.x * 32;
#pragma unroll
    for (int i = ty; i < 32; i += 8) {
        int cc = c0 + i;
        if (cc < C && rr < R) dst[(size_t)cc * R + rr] = f2h(tile[tx][i]);
    }
}

// ---------------- pack Wq+Wo (fp32 [640][640]) into fragment-linear f16 (z picks) ----------------
__global__ void pack_wfrag2(const float* __restrict__ Wq, const float* __restrict__ Wo,
                            ushort* __restrict__ WqF, ushort* __restrict__ WoF) {
    int g = blockIdx.x * 256 + threadIdx.x;   // 0 .. 51199
    if (g >= 51200) return;
    const float* W = blockIdx.y ? Wo : Wq;
    ushort* WF = blockIdx.y ? WoF : WqF;
    int lane = g & 63;
    int fi = (g >> 6) % 10;
    int kt = ((g >> 6) / 10) % 10;
    int h  = (g >> 6) / 100;
    int ni = fi >> 1, kk = fi & 1;
    int n  = h * 80 + ni * 16 + (lane & 15);
    int k0 = kt * 64 + kk * 32 + (lane >> 4) * 8;
    u16x8 o;
#pragma unroll
    for (int e = 0; e < 8; ++e) o[e] = f2h(W[(size_t)(k0 + e) * 640 + n]);
    *(u16x8*)&WF[(size_t)g * 8] = o;
}

// ---------------- pack K,V fragments from KVb ----------------
__global__ void pack_kvfrag(const ushort* __restrict__ KVb,
                            ushort* __restrict__ KF, ushort* __restrict__ VF) {
    int g = blockIdx.x * 256 + threadIdx.x;   // 0 .. 61439
    if (g >= 61440) return;
    int lane = g & 63;
    int fi = (g >> 6) % 15;
    int bh = (g >> 6) / 15;
    int b = bh >> 3, h = bh & 7;
    int ni = fi / 3, kk = fi % 3;
    int l15 = lane & 15, lhi = lane >> 4;
    int sr = ni * 16 + l15; if (sr > 76) sr = 76;
    int d0 = kk * 32 + lhi * 8;
    u16x8 ko, vo;
#pragma unroll
    for (int e = 0; e < 8; ++e)
        ko[e] = KVb[((size_t)b * 77 + sr) * 1280 + h * 80 + d0 + e];
    int dv = ni * 16 + l15;
    int s0 = kk * 32 + lhi * 8;
#pragma unroll
    for (int e = 0; e < 8; ++e) {
        int s = s0 + e;
        vo[e] = (s < 77) ? KVb[((size_t)b * 77 + s) * 1280 + 640 + h * 80 + dv] : (ushort)0;
    }
    *(u16x8*)&KF[(size_t)g * 8] = ko;
    *(u16x8*)&VF[(size_t)g * 8] = vo;
}

// ---------------- 128x128 GEMM (for the tiny KV projection) ----------------
template<int OUT_F16, int HAS_BIAS>
__global__ __launch_bounds__(256) void gemm_bt(
    const ushort* __restrict__ A, const ushort* __restrict__ Bt,
    void* __restrict__ C, const float* __restrict__ bias,
    int M, int N, int K)
{
    __shared__ ushort As[128 * 64];
    __shared__ ushort Bs[128 * 64];
    const int tid = threadIdx.x;
    const int lane = tid & 63;
    const int w = tid >> 6;
    const int wr = (w >> 1) * 64, wc = (w & 1) * 64;
    const int m0 = blockIdx.x * 128, n0 = blockIdx.y * 128;
    const int l15 = lane & 15, lhi = lane >> 4;

    f32x4 acc[4][4] = {};

    for (int k0 = 0; k0 < K; k0 += 64) {
        __syncthreads();
#pragma unroll
        for (int i = 0; i < 4; ++i) {
            int c = i * 256 + tid;
            int m = m0 + (c >> 3);
            if (m > M - 1) m = M - 1;
            GLOAD_LDS16(A + (size_t)m * K + k0 + (c & 7) * 8, &As[c * 8]);
        }
#pragma unroll
        for (int i = 0; i < 4; ++i) {
            int c = i * 256 + tid;
            GLOAD_LDS16(Bt + (size_t)(n0 + (c >> 3)) * K + k0 + (c & 7) * 8, &Bs[c * 8]);
        }
        __syncthreads();
#pragma unroll
        for (int kk = 0; kk < 2; ++kk) {
            f16x8 af[4], bfr[4];
#pragma unroll
            for (int mi = 0; mi < 4; ++mi)
                af[mi] = *(const f16x8*)&As[(wr + mi * 16 + l15) * 64 + kk * 32 + lhi * 8];
#pragma unroll
            for (int ni = 0; ni < 4; ++ni)
                bfr[ni] = *(const f16x8*)&Bs[(wc + ni * 16 + l15) * 64 + kk * 32 + lhi * 8];
#pragma unroll
            for (int mi = 0; mi < 4; ++mi)
#pragma unroll
                for (int ni = 0; ni < 4; ++ni)
                    acc[mi][ni] = __builtin_amdgcn_mfma_f32_16x16x32_f16(
                        af[mi], bfr[ni], acc[mi][ni], 0, 0, 0);
        }
    }

#pragma unroll
    for (int mi = 0; mi < 4; ++mi)
#pragma unroll
        for (int ni = 0; ni < 4; ++ni)
#pragma unroll
            for (int r = 0; r < 4; ++r) {
                int row = m0 + wr + mi * 16 + lhi * 4 + r;
                int col = n0 + wc + ni * 16 + l15;
                if (row < M) {
                    float v = acc[mi][ni][r];
                    if (HAS_BIAS) v += bias[col];
                    if (OUT_F16) ((ushort*)C)[(size_t)row * N + col] = f2h(v);
                    else         ((float*)C)[(size_t)row * N + col] = v;
                }
            }
}

// ================= fused: tokens->Q-proj->attention->O-proj->out =================
// R14 = R8 geometry (64-row blocks, 8 waves = 8 heads, 512 blocks: best W-amortization
// without spill) + per-wave COUNTED-vmcnt B pipeline:
//   B-frags flow through private per-wave LDS strips via global_load_lds (no VGPR
//   cost, no cross-wave sync: strip is wave-private so NO barrier protects it).
//   Q-proj: 3 slots x 2560 ushorts, issued 2 halves ahead, consumed at vmcnt(10)
//   (tails 10/5/0 — exact counts derived from the static issue order incl. token
//   loads). O-proj: 2 slots, distance 1, vmcnt(5). Loads stay in flight ACROSS the
//   per-kt token barriers — what R8's register dbuf couldn't do (compiler drains).
// LDS (ushort offsets): toks dbuf 0/4096 ([64][64] swz); Q-strips 8192 + w*7680;
//   Q/P [64][80] @ w*5120 (alias, post-Q); ctxall [0,40960) + O-strips 40960+w*5120.
__global__ __launch_bounds__(512, 2) void fused_attn(
    const float* __restrict__ tokens, const ushort* __restrict__ WqF,
    const ushort* __restrict__ KF, const ushort* __restrict__ VF,
    const ushort* __restrict__ WoF, const float* __restrict__ bo,
    float* __restrict__ out)
{
    __shared__ __align__(16) ushort lds[81920];   // 160 KiB
    const int tid = threadIdx.x;
    const int lane = tid & 63;
    const int w = tid >> 6;
    const int l15 = lane & 15, lhi = lane >> 4;
    const int tt = blockIdx.x, b = blockIdx.y;
    const size_t rowbase = (size_t)b * 4096 + (size_t)tt * 64;

    const ushort* WqFb = WqF + (size_t)w * 10 * 5120;
    const ushort* WoFb = WoF + (size_t)w * 10 * 5120;
    const ushort* KFb  = KF + (size_t)(b * 8 + w) * 15 * 512;
    const ushort* VFb  = VF + (size_t)(b * 8 + w) * 15 * 512;
    const int qstrip = 8192 + w * 7680;    // 3 slots x 2560
    const int ostrip = 40960 + w * 5120;   // 2 slots x 2560

    // token staging: each thread loads 8 f32 (2 float4) per 64x64 chunk
    const int srow = tid >> 3;             // 0..63
    const int sc8  = tid & 7;
    const int sphys = (sc8 ^ (srow & 7)) * 8;

#define STAGE_LOAD(C, A0, B0) do { \
    const float* p_ = tokens + (rowbase + srow) * 640 + (C) * 64 + sc8 * 8; \
    A0 = ((const float4*)p_)[0]; B0 = ((const float4*)p_)[1]; \
} while (0)
#define STAGE_WRITE(BUF, A0, B0) do { \
    u16x8 o_; \
    o_[0]=f2h(A0.x); o_[1]=f2h(A0.y); o_[2]=f2h(A0.z); o_[3]=f2h(A0.w); \
    o_[4]=f2h(B0.x); o_[5]=f2h(B0.y); o_[6]=f2h(B0.z); o_[7]=f2h(B0.w); \
    *(u16x8*)&lds[(BUF) * 4096 + srow * 64 + sphys] = o_; \
} while (0)

// issue one B half (5 frags, 1 KB each) into q-strip slot HX%3 (wave-private, async)
#define GLOADB_Q(HX) do { \
    if ((HX) <= 19) { \
        const ushort* s_ = WqFb + ((HX) >> 1) * 5120 + ((HX) & 1) * 512 + lane * 8; \
        _Pragma("unroll") for (int f_ = 0; f_ < 5; ++f_) \
            GLOAD_LDS16(s_ + f_ * 1024, &lds[qstrip + ((HX) % 3) * 2560 + f_ * 512]); \
    } \
} while (0)
#define GLOADB_O(HX) do { \
    if ((HX) <= 19) { \
        const ushort* s_ = WoFb + ((HX) >> 1) * 5120 + ((HX) & 1) * 512 + lane * 8; \
        _Pragma("unroll") for (int f_ = 0; f_ < 5; ++f_) \
            GLOAD_LDS16(s_ + f_ * 1024, &lds[ostrip + ((HX) & 1) * 2560 + f_ * 512]); \
    } \
} while (0)

    f32x4 acc[4][5];
#define ZACC() do { \
    _Pragma("unroll") for (int i_ = 0; i_ < 4; ++i_) \
    _Pragma("unroll") for (int j_ = 0; j_ < 5; ++j_) \
        acc[i_][j_] = (f32x4){0.f, 0.f, 0.f, 0.f}; \
} while (0)

#define MFMA_Q(KT, KK) do { \
    f16x8 bf_[5]; \
    _Pragma("unroll") for (int ni = 0; ni < 5; ++ni) \
        bf_[ni] = *(const f16x8*)&lds[qstrip + ((2*(KT)+(KK)) % 3) * 2560 + ni * 512 + lane * 8]; \
    PRIO1(); \
    _Pragma("unroll") for (int mi = 0; mi < 4; ++mi) { \
        int row_ = mi * 16 + l15; \
        f16x8 a_ = *(const f16x8*)&lds[((KT) & 1) * 4096 + row_ * 64 + (((KK)*4 + lhi) ^ (row_ & 7)) * 8]; \
        _Pragma("unroll") for (int ni = 0; ni < 5; ++ni) \
            acc[mi][ni] = __builtin_amdgcn_mfma_f32_16x16x32_f16(a_, bf_[ni], acc[mi][ni], 0, 0, 0); \
    } \
    PRIO0(); \
} while (0)
#define MFMA_O(HX) do { \
    f16x8 bf_[5]; \
    _Pragma("unroll") for (int ni = 0; ni < 5; ++ni) \
        bf_[ni] = *(const f16x8*)&lds[ostrip + ((HX) & 1) * 2560 + ni * 512 + lane * 8]; \
    PRIO1(); \
    _Pragma("unroll") for (int mi = 0; mi < 4; ++mi) { \
        int row_ = mi * 16 + l15; \
        f16x8 a_ = *(const f16x8*)&lds[row_ * 640 + (((HX) >> 1) * 8 + ((((HX) & 1)*4 + lhi) ^ (row_ & 7))) * 8]; \
        _Pragma("unroll") for (int ni = 0; ni < 5; ++ni) \
            acc[mi][ni] = __builtin_amdgcn_mfma_f32_16x16x32_f16(a_, bf_[ni], acc[mi][ni], 0, 0, 0); \
    } \
    PRIO0(); \
} while (0)

// one Q-proj kt: issue tok(kt+2) + B(2kt+2); wait; write tok(kt+1); MFMA h0;
//                issue B(2kt+3); wait; MFMA h1; barrier.
#define QKT(KT, WA, WB, LA, LB, WRA, WRB) do { \
    if ((KT) < 8) STAGE_LOAD((KT) + 2, LA, LB); \
    GLOADB_Q(2*(KT) + 2); \
    WAITVM(WA); \
    if ((KT) < 9) STAGE_WRITE(((KT)+1) & 1, WRA, WRB); \
    MFMA_Q(KT, 0); \
    GLOADB_Q(2*(KT) + 3); \
    WAITVM(WB); \
    MFMA_Q(KT, 1); \
    __syncthreads(); \
} while (0)

    // ---- prologue: tok0,tok1 loads; B0,B1 strips; write tok0 ----
    float4 sA0, sB0, sA1, sB1;
    STAGE_LOAD(0, sA0, sB0);
    STAGE_LOAD(1, sA1, sB1);
    GLOADB_Q(0);
    GLOADB_Q(1);
    WAITVM(10);                 // tok0,tok1 done (B0,B1 = 10 newer)
    STAGE_WRITE(0, sA0, sB0);
    __syncthreads();

    // ---- Q projection, counted-vmcnt pipeline ----
    ZACC();
    QKT(0, 10, 10, sA0, sB0, sA1, sB1);
    QKT(1, 10, 10, sA1, sB1, sA0, sB0);
    QKT(2, 10, 10, sA0, sB0, sA1, sB1);
    QKT(3, 10, 10, sA1, sB1, sA0, sB0);
    QKT(4, 10, 10, sA0, sB0, sA1, sB1);
    QKT(5, 10, 10, sA1, sB1, sA0, sB0);
    QKT(6, 10, 10, sA0, sB0, sA1, sB1);
    QKT(7, 10, 10, sA1, sB1, sA0, sB0);
    QKT(8, 10, 10, sA0, sB0, sA1, sB1);   // no tok issue (guard); writes tok9
    QKT(9,  5,  0, sA0, sB0, sA1, sB1);   // tail: no issues, drain 5 then 0
#undef QKT

    // ---- write Q f16 into per-wave [64][80] region (aliases toks+low strips) ----
    const int qoff = w * 5120;
#pragma unroll
    for (int mi = 0; mi < 4; ++mi)
#pragma unroll
        for (int ni = 0; ni < 5; ++ni)
#pragma unroll
            for (int r = 0; r < 4; ++r)
                lds[qoff + (mi*16 + lhi*4 + r)*80 + ni*16 + l15] = f2h(acc[mi][ni][r]);
    __builtin_amdgcn_sched_barrier(0);

    const f16x8 zf = {};
    f16x8 PE[5], PO[5];
#define ATT_KK(PC, PN, FB, KK, NKK, DOPF) do { \
    if (DOPF) { \
        _Pragma("unroll") for (int f = 0; f < 5; ++f) \
            (PN)[f] = *(const f16x8*)((FB) + (f * 3 + (NKK)) * 512 + lane * 8); \
    } \
    const int kcol = ((KK) < 2) ? ((KK)*32 + lhi*8) : (64 + (lhi & 1)*8); \
    PRIO1(); \
    _Pragma("unroll") for (int mi = 0; mi < 4; ++mi) { \
        f16x8 aq_ = *(const f16x8*)&lds[qoff + (mi*16 + l15)*80 + kcol]; \
        if ((KK) == 2 && lhi >= 2) aq_ = zf; \
        _Pragma("unroll") for (int ni = 0; ni < 5; ++ni) \
            acc[mi][ni] = __builtin_amdgcn_mfma_f32_16x16x32_f16(aq_, (PC)[ni], acc[mi][ni], 0, 0, 0); \
    } \
    PRIO0(); \
} while (0)

    // ---- S = Q K^T ----
    ZACC();
#pragma unroll
    for (int f = 0; f < 5; ++f)
        PE[f] = *(const f16x8*)(KFb + (f * 3) * 512 + lane * 8);
    ATT_KK(PE, PO, KFb, 0, 1, 1);
    ATT_KK(PO, PE, KFb, 1, 2, 1);
    ATT_KK(PE, PO, KFb, 2, 0, 0);
    __builtin_amdgcn_sched_barrier(0);

    // ---- softmax over s (77 valid), P f16 back into Q/P region ----
    const float sc = 0.11180339887498949f;   // 1/sqrt(80)
#pragma unroll
    for (int mi = 0; mi < 4; ++mi)
#pragma unroll
        for (int r = 0; r < 4; ++r) {
            float v0 = acc[mi][0][r]*sc, v1 = acc[mi][1][r]*sc, v2 = acc[mi][2][r]*sc,
                  v3 = acc[mi][3][r]*sc, v4 = acc[mi][4][r]*sc;
            bool ok4 = l15 < 13;
            float mx = fmaxf(fmaxf(v0, v1), fmaxf(v2, v3));
            if (ok4) mx = fmaxf(mx, v4);
#pragma unroll
            for (int off = 1; off < 16; off <<= 1) mx = fmaxf(mx, __shfl_xor(mx, off, 16));
            float p0 = __expf(v0-mx), p1 = __expf(v1-mx), p2 = __expf(v2-mx), p3 = __expf(v3-mx);
            float p4 = ok4 ? __expf(v4-mx) : 0.f;
            float sm = p0+p1+p2+p3+p4;
#pragma unroll
            for (int off = 1; off < 16; off <<= 1) sm += __shfl_xor(sm, off, 16);
            float inv = 1.f / sm;
            int row = mi*16 + lhi*4 + r;
            lds[qoff + row*80 + 0*16 + l15] = f2h(p0*inv);
            lds[qoff + row*80 + 1*16 + l15] = f2h(p1*inv);
            lds[qoff + row*80 + 2*16 + l15] = f2h(p2*inv);
            lds[qoff + row*80 + 3*16 + l15] = f2h(p3*inv);
            lds[qoff + row*80 + 4*16 + l15] = f2h(p4*inv);
        }
    __builtin_amdgcn_sched_barrier(0);

    // ---- O = P V ----
    ZACC();
#pragma unroll
    for (int f = 0; f < 5; ++f)
        PE[f] = *(const f16x8*)(VFb + (f * 3) * 512 + lane * 8);
    ATT_KK(PE, PO, VFb, 0, 1, 1);
    ATT_KK(PO, PE, VFb, 1, 2, 1);
    ATT_KK(PE, PO, VFb, 2, 0, 0);
#undef ATT_KK

    // issue O-proj B(0) early (region disjoint from live Q/P); latency hides here
    GLOADB_O(0);
    __syncthreads();                      // Q/P regions dead everywhere

    // ---- ctxall [64][640] swizzled = concat of heads ----
#pragma unroll
    for (int mi = 0; mi < 4; ++mi)
#pragma unroll
        for (int ni = 0; ni < 5; ++ni)
#pragma unroll
            for (int r = 0; r < 4; ++r) {
                int row = mi*16 + lhi*4 + r;
                int col = w*80 + ni*16 + l15;
                int slot = col >> 3;
                int phys = (slot & ~7) | ((slot ^ row) & 7);
                lds[row*640 + phys*8 + (col & 7)] = f2h(acc[mi][ni][r]);
            }
    __syncthreads();                      // ctxall ready

    // ---- O projection: counted-vmcnt, 2-slot distance-1 pipeline ----
    ZACC();
#define OH(HX, W) do { GLOADB_O((HX) + 1); WAITVM(W); MFMA_O(HX); } while (0)
    OH(0, 5);  OH(1, 5);  OH(2, 5);  OH(3, 5);  OH(4, 5);
    OH(5, 5);  OH(6, 5);  OH(7, 5);  OH(8, 5);  OH(9, 5);
    OH(10, 5); OH(11, 5); OH(12, 5); OH(13, 5); OH(14, 5);
    OH(15, 5); OH(16, 5); OH(17, 5); OH(18, 5); OH(19, 0);
#undef OH

    // ---- epilogue: f32 out + bias ----
#pragma unroll
    for (int ni = 0; ni < 5; ++ni) {
        int col = w*80 + ni*16 + l15;
        float bvl = bo[col];
#pragma unroll
        for (int mi = 0; mi < 4; ++mi)
#pragma unroll
            for (int r = 0; r < 4; ++r)
                out[(rowbase + mi*16 + lhi*4 + r) * 640 + col] = acc[mi][ni][r] + bvl;
    }
#undef STAGE_LOAD
#undef STAGE_WRITE
#undef GLOADB_Q
#undef GLOADB_O
#undef MFMA_Q
#undef MFMA_O
#undef ZACC
}

extern "C" void kernel_launch(void* const* d_in, const int* in_sizes, int n_in,
                              void* d_out, int out_size, void* d_ws, size_t ws_size,
                              hipStream_t stream) {
    (void)in_sizes; (void)n_in; (void)out_size; (void)ws_size;
    const float* tokens  = (const float*)d_in[0];
    const float* context = (const float*)d_in[1];
    const float* Wq = (const float*)d_in[2];
    const float* Wk = (const float*)d_in[3];
    const float* Wv = (const float*)d_in[4];
    const float* Wo = (const float*)d_in[5];
    const float* bo = (const float*)d_in[6];
    float* out = (float*)d_out;

    ushort* ws   = (ushort*)d_ws;
    ushort* ctx16 = ws;                                   // 616*768
    ushort* WkvT = ctx16 + (size_t)616 * 768;             // 1280*768
    ushort* KVb  = WkvT + (size_t)1280 * 768;             // 616*1280
    ushort* WqF  = KVb  + (size_t)616 * 1280;             // 640*640
    ushort* WoF  = WqF  + (size_t)640 * 640;              // 640*640
    ushort* KF   = WoF  + (size_t)640 * 640;              // 61440*8
    ushort* VF   = KF   + (size_t)61440 * 8;              // 61440*8

    cvt_kernel<<<462, 256, 0, stream>>>(context, ctx16, 616 * 768 / 4);
    transpose_cvt2<<<dim3(20, 24, 2), dim3(32, 8), 0, stream>>>(Wk, Wv, WkvT);
    pack_wfrag2<<<dim3(200, 2), 256, 0, stream>>>(Wq, Wo, WqF, WoF);
    gemm_bt<1, 0><<<dim3(5, 10), 256, 0, stream>>>(ctx16, WkvT, KVb, nullptr, 616, 1280, 768);
    pack_kvfrag<<<240, 256, 0, stream>>>(KVb, KF, VF);
    fused_attn<<<dim3(64, 8), 512, 0, stream>>>(tokens, WqF, KF, VF, WoF, bo, out);
}

// Round 15
// 124.581 us; speedup vs baseline: 1.0866x; 1.0212x over previous
//
#include <hip/hip_runtime.h>
#include <hip/hip_bf16.h>
#include <hip/hip_fp16.h>

typedef __attribute__((ext_vector_type(4))) float f32x4;
typedef __attribute__((ext_vector_type(8))) _Float16 f16x8;
typedef __attribute__((ext_vector_type(8))) unsigned short u16x8;

__device__ __forceinline__ unsigned short f2h(float f) {
    _Float16 h = (_Float16)f;
    return __builtin_bit_cast(unsigned short, h);
}

#define GLOAD_LDS16(gp, lp) __builtin_amdgcn_global_load_lds( \
    (const __attribute__((address_space(1))) void*)(gp), \
    (__attribute__((address_space(3))) void*)(lp), 16, 0, 0)
#define PRIO1() __builtin_amdgcn_s_setprio(1)
#define PRIO0() __builtin_amdgcn_s_setprio(0)
// counted vmcnt with literal, plus sched fence (rule #18 analog)
#define WAITVM(LIT) do { asm volatile("s_waitcnt vmcnt(" #LIT ")" ::: "memory"); \
                         __builtin_amdgcn_sched_barrier(0); } while (0)
// barrier WITHOUT vmcnt drain: drain only LDS ops (my ds_writes), raw s_barrier.
// __syncthreads() emits s_waitcnt vmcnt(0) lgkmcnt(0) -> killed the counted-vmcnt
// pipeline every kt in R8-R14. Raw s_barrier + lgkmcnt(0) keeps B loads in flight.
#define BARND() do { asm volatile("s_waitcnt lgkmcnt(0)" ::: "memory"); \
                     __builtin_amdgcn_sched_barrier(0); \
                     __builtin_amdgcn_s_barrier(); \
                     __builtin_amdgcn_sched_barrier(0); } while (0)

// ---------------- fp32 -> fp16 elementwise convert (vectorized) ----------------
__global__ void cvt_kernel(const float* __restrict__ in, ushort* __restrict__ out, int n4) {
    int stride = gridDim.x * blockDim.x;
    for (int i = blockIdx.x * blockDim.x + threadIdx.x; i < n4; i += stride) {
        float4 v = ((const float4*)in)[i];
        ushort4 o;
        o.x = f2h(v.x); o.y = f2h(v.y); o.z = f2h(v.z); o.w = f2h(v.w);
        ((ushort4*)out)[i] = o;
    }
}

// ---------------- transpose + convert Wk/Wv (for the KV projection GEMM) ----------------
__global__ void transpose_cvt2(const float* __restrict__ Wk, const float* __restrict__ Wv,
                               ushort* __restrict__ WkvT) {
    __shared__ float tile[32][33];
    const int z = blockIdx.z;
    const float* src = z ? Wv : Wk;
    ushort* dst = WkvT + (size_t)z * 640 * 768;
    const int R = 768, C = 640;
    int tx = threadIdx.x, ty = threadIdx.y;
    int c = blockIdx.x * 32 + tx;
    int r0 = blockIdx.y * 32;
#pragma unroll
    for (int i = ty; i < 32; i += 8) {
        int r = r0 + i;
        tile[i][tx] = (r < R && c < C) ? src[(size_t)r * C + c] : 0.f;
    }
    __syncthreads();
    int rr = r0 + tx;
    int c0 = blockIdx.x * 32;
#pragma unroll
    for (int i = ty; i < 32; i += 8) {
        int cc = c0 + i;
        if (cc < C && rr < R) dst[(size_t)cc * R + rr] = f2h(tile[tx][i]);
    }
}

// ---------------- pack Wq+Wo (fp32 [640][640]) into fragment-linear f16 (y picks) ----------------
__global__ void pack_wfrag2(const float* __restrict__ Wq, const float* __restrict__ Wo,
                            ushort* __restrict__ WqF, ushort* __restrict__ WoF) {
    int g = blockIdx.x * 256 + threadIdx.x;   // 0 .. 51199
    if (g >= 51200) return;
    const float* W = blockIdx.y ? Wo : Wq;
    ushort* WF = blockIdx.y ? WoF : WqF;
    int lane = g & 63;
    int fi = (g >> 6) % 10;
    int kt = ((g >> 6) / 10) % 10;
    int h  = (g >> 6) / 100;
    int ni = fi >> 1, kk = fi & 1;
    int n  = h * 80 + ni * 16 + (lane & 15);
    int k0 = kt * 64 + kk * 32 + (lane >> 4) * 8;
    u16x8 o;
#pragma unroll
    for (int e = 0; e < 8; ++e) o[e] = f2h(W[(size_t)(k0 + e) * 640 + n]);
    *(u16x8*)&WF[(size_t)g * 8] = o;
}

// ---------------- pack K,V fragments from KVb ----------------
__global__ void pack_kvfrag(const ushort* __restrict__ KVb,
                            ushort* __restrict__ KF, ushort* __restrict__ VF) {
    int g = blockIdx.x * 256 + threadIdx.x;   // 0 .. 61439
    if (g >= 61440) return;
    int lane = g & 63;
    int fi = (g >> 6) % 15;
    int bh = (g >> 6) / 15;
    int b = bh >> 3, h = bh & 7;
    int ni = fi / 3, kk = fi % 3;
    int l15 = lane & 15, lhi = lane >> 4;
    int sr = ni * 16 + l15; if (sr > 76) sr = 76;
    int d0 = kk * 32 + lhi * 8;
    u16x8 ko, vo;
#pragma unroll
    for (int e = 0; e < 8; ++e)
        ko[e] = KVb[((size_t)b * 77 + sr) * 1280 + h * 80 + d0 + e];
    int dv = ni * 16 + l15;
    int s0 = kk * 32 + lhi * 8;
#pragma unroll
    for (int e = 0; e < 8; ++e) {
        int s = s0 + e;
        vo[e] = (s < 77) ? KVb[((size_t)b * 77 + s) * 1280 + 640 + h * 80 + dv] : (ushort)0;
    }
    *(u16x8*)&KF[(size_t)g * 8] = ko;
    *(u16x8*)&VF[(size_t)g * 8] = vo;
}

// ---------------- 128x128 GEMM (for the tiny KV projection) ----------------
template<int OUT_F16, int HAS_BIAS>
__global__ __launch_bounds__(256) void gemm_bt(
    const ushort* __restrict__ A, const ushort* __restrict__ Bt,
    void* __restrict__ C, const float* __restrict__ bias,
    int M, int N, int K)
{
    __shared__ ushort As[128 * 64];
    __shared__ ushort Bs[128 * 64];
    const int tid = threadIdx.x;
    const int lane = tid & 63;
    const int w = tid >> 6;
    const int wr = (w >> 1) * 64, wc = (w & 1) * 64;
    const int m0 = blockIdx.x * 128, n0 = blockIdx.y * 128;
    const int l15 = lane & 15, lhi = lane >> 4;

    f32x4 acc[4][4] = {};

    for (int k0 = 0; k0 < K; k0 += 64) {
        __syncthreads();
#pragma unroll
        for (int i = 0; i < 4; ++i) {
            int c = i * 256 + tid;
            int m = m0 + (c >> 3);
            if (m > M - 1) m = M - 1;
            GLOAD_LDS16(A + (size_t)m * K + k0 + (c & 7) * 8, &As[c * 8]);
        }
#pragma unroll
        for (int i = 0; i < 4; ++i) {
            int c = i * 256 + tid;
            GLOAD_LDS16(Bt + (size_t)(n0 + (c >> 3)) * K + k0 + (c & 7) * 8, &Bs[c * 8]);
        }
        __syncthreads();
#pragma unroll
        for (int kk = 0; kk < 2; ++kk) {
            f16x8 af[4], bfr[4];
#pragma unroll
            for (int mi = 0; mi < 4; ++mi)
                af[mi] = *(const f16x8*)&As[(wr + mi * 16 + l15) * 64 + kk * 32 + lhi * 8];
#pragma unroll
            for (int ni = 0; ni < 4; ++ni)
                bfr[ni] = *(const f16x8*)&Bs[(wc + ni * 16 + l15) * 64 + kk * 32 + lhi * 8];
#pragma unroll
            for (int mi = 0; mi < 4; ++mi)
#pragma unroll
                for (int ni = 0; ni < 4; ++ni)
                    acc[mi][ni] = __builtin_amdgcn_mfma_f32_16x16x32_f16(
                        af[mi], bfr[ni], acc[mi][ni], 0, 0, 0);
        }
    }

#pragma unroll
    for (int mi = 0; mi < 4; ++mi)
#pragma unroll
        for (int ni = 0; ni < 4; ++ni)
#pragma unroll
            for (int r = 0; r < 4; ++r) {
                int row = m0 + wr + mi * 16 + lhi * 4 + r;
                int col = n0 + wc + ni * 16 + l15;
                if (row < M) {
                    float v = acc[mi][ni][r];
                    if (HAS_BIAS) v += bias[col];
                    if (OUT_F16) ((ushort*)C)[(size_t)row * N + col] = f2h(v);
                    else         ((float*)C)[(size_t)row * N + col] = v;
                }
            }
}

// ================= fused: tokens->Q-proj->attention->O-proj->out =================
// R15 = R14 with ONE change: all in-loop __syncthreads() replaced by BARND()
// (lgkmcnt(0) + raw s_barrier). __syncthreads' implicit vmcnt(0) drained the
// counted-vmcnt B pipeline at every kt — R8-R14's common ~105us floor. Raw
// barriers let the per-wave B-strip global_load_lds stream flow continuously
// across kt boundaries (per-CU L2 stream is the binding resource: 80KB/kt vs
// 780cy MFMA). Wait counts identical to R14 (validated by absmax 0.0039).
__global__ __launch_bounds__(512, 2) void fused_attn(
    const float* __restrict__ tokens, const ushort* __restrict__ WqF,
    const ushort* __restrict__ KF, const ushort* __restrict__ VF,
    const ushort* __restrict__ WoF, const float* __restrict__ bo,
    float* __restrict__ out)
{
    __shared__ __align__(16) ushort lds[81920];   // 160 KiB
    const int tid = threadIdx.x;
    const int lane = tid & 63;
    const int w = tid >> 6;
    const int l15 = lane & 15, lhi = lane >> 4;
    const int tt = blockIdx.x, b = blockIdx.y;
    const size_t rowbase = (size_t)b * 4096 + (size_t)tt * 64;

    const ushort* WqFb = WqF + (size_t)w * 10 * 5120;
    const ushort* WoFb = WoF + (size_t)w * 10 * 5120;
    const ushort* KFb  = KF + (size_t)(b * 8 + w) * 15 * 512;
    const ushort* VFb  = VF + (size_t)(b * 8 + w) * 15 * 512;
    const int qstrip = 8192 + w * 7680;    // 3 slots x 2560
    const int ostrip = 40960 + w * 5120;   // 2 slots x 2560

    // token staging: each thread loads 8 f32 (2 float4) per 64x64 chunk
    const int srow = tid >> 3;             // 0..63
    const int sc8  = tid & 7;
    const int sphys = (sc8 ^ (srow & 7)) * 8;

#define STAGE_LOAD(C, A0, B0) do { \
    const float* p_ = tokens + (rowbase + srow) * 640 + (C) * 64 + sc8 * 8; \
    A0 = ((const float4*)p_)[0]; B0 = ((const float4*)p_)[1]; \
} while (0)
#define STAGE_WRITE(BUF, A0, B0) do { \
    u16x8 o_; \
    o_[0]=f2h(A0.x); o_[1]=f2h(A0.y); o_[2]=f2h(A0.z); o_[3]=f2h(A0.w); \
    o_[4]=f2h(B0.x); o_[5]=f2h(B0.y); o_[6]=f2h(B0.z); o_[7]=f2h(B0.w); \
    *(u16x8*)&lds[(BUF) * 4096 + srow * 64 + sphys] = o_; \
} while (0)

// issue one B half (5 frags, 1 KB each) into q-strip slot HX%3 (wave-private, async)
#define GLOADB_Q(HX) do { \
    if ((HX) <= 19) { \
        const ushort* s_ = WqFb + ((HX) >> 1) * 5120 + ((HX) & 1) * 512 + lane * 8; \
        _Pragma("unroll") for (int f_ = 0; f_ < 5; ++f_) \
            GLOAD_LDS16(s_ + f_ * 1024, &lds[qstrip + ((HX) % 3) * 2560 + f_ * 512]); \
    } \
} while (0)
#define GLOADB_O(HX) do { \
    if ((HX) <= 19) { \
        const ushort* s_ = WoFb + ((HX) >> 1) * 5120 + ((HX) & 1) * 512 + lane * 8; \
        _Pragma("unroll") for (int f_ = 0; f_ < 5; ++f_) \
            GLOAD_LDS16(s_ + f_ * 1024, &lds[ostrip + ((HX) & 1) * 2560 + f_ * 512]); \
    } \
} while (0)

    f32x4 acc[4][5];
#define ZACC() do { \
    _Pragma("unroll") for (int i_ = 0; i_ < 4; ++i_) \
    _Pragma("unroll") for (int j_ = 0; j_ < 5; ++j_) \
        acc[i_][j_] = (f32x4){0.f, 0.f, 0.f, 0.f}; \
} while (0)

#define MFMA_Q(KT, KK) do { \
    f16x8 bf_[5]; \
    _Pragma("unroll") for (int ni = 0; ni < 5; ++ni) \
        bf_[ni] = *(const f16x8*)&lds[qstrip + ((2*(KT)+(KK)) % 3) * 2560 + ni * 512 + lane * 8]; \
    PRIO1(); \
    _Pragma("unroll") for (int mi = 0; mi < 4; ++mi) { \
        int row_ = mi * 16 + l15; \
        f16x8 a_ = *(const f16x8*)&lds[((KT) & 1) * 4096 + row_ * 64 + (((KK)*4 + lhi) ^ (row_ & 7)) * 8]; \
        _Pragma("unroll") for (int ni = 0; ni < 5; ++ni) \
            acc[mi][ni] = __builtin_amdgcn_mfma_f32_16x16x32_f16(a_, bf_[ni], acc[mi][ni], 0, 0, 0); \
    } \
    PRIO0(); \
} while (0)
#define MFMA_O(HX) do { \
    f16x8 bf_[5]; \
    _Pragma("unroll") for (int ni = 0; ni < 5; ++ni) \
        bf_[ni] = *(const f16x8*)&lds[ostrip + ((HX) & 1) * 2560 + ni * 512 + lane * 8]; \
    PRIO1(); \
    _Pragma("unroll") for (int mi = 0; mi < 4; ++mi) { \
        int row_ = mi * 16 + l15; \
        f16x8 a_ = *(const f16x8*)&lds[row_ * 640 + (((HX) >> 1) * 8 + ((((HX) & 1)*4 + lhi) ^ (row_ & 7))) * 8]; \
        _Pragma("unroll") for (int ni = 0; ni < 5; ++ni) \
            acc[mi][ni] = __builtin_amdgcn_mfma_f32_16x16x32_f16(a_, bf_[ni], acc[mi][ni], 0, 0, 0); \
    } \
    PRIO0(); \
} while (0)

// one Q-proj kt: issue tok(kt+2) + B(2kt+2); wait; write tok(kt+1); MFMA h0;
//                issue B(2kt+3); wait; MFMA h1; raw barrier (no vmcnt drain).
#define QKT(KT, WA, WB, LA, LB, WRA, WRB) do { \
    if ((KT) < 8) STAGE_LOAD((KT) + 2, LA, LB); \
    GLOADB_Q(2*(KT) + 2); \
    WAITVM(WA); \
    if ((KT) < 9) STAGE_WRITE(((KT)+1) & 1, WRA, WRB); \
    MFMA_Q(KT, 0); \
    GLOADB_Q(2*(KT) + 3); \
    WAITVM(WB); \
    MFMA_Q(KT, 1); \
    BARND(); \
} while (0)

    // ---- prologue: tok0,tok1 loads; B0,B1 strips; write tok0 ----
    float4 sA0, sB0, sA1, sB1;
    STAGE_LOAD(0, sA0, sB0);
    STAGE_LOAD(1, sA1, sB1);
    GLOADB_Q(0);
    GLOADB_Q(1);
    WAITVM(10);                 // tok0,tok1 done (B0,B1 = 10 newer, stay in flight)
    STAGE_WRITE(0, sA0, sB0);
    BARND();

    // ---- Q projection, counted-vmcnt pipeline (loads survive barriers now) ----
    ZACC();
    QKT(0, 10, 10, sA0, sB0, sA1, sB1);
    QKT(1, 10, 10, sA1, sB1, sA0, sB0);
    QKT(2, 10, 10, sA0, sB0, sA1, sB1);
    QKT(3, 10, 10, sA1, sB1, sA0, sB0);
    QKT(4, 10, 10, sA0, sB0, sA1, sB1);
    QKT(5, 10, 10, sA1, sB1, sA0, sB0);
    QKT(6, 10, 10, sA0, sB0, sA1, sB1);
    QKT(7, 10, 10, sA1, sB1, sA0, sB0);
    QKT(8, 10, 10, sA0, sB0, sA1, sB1);   // no tok issue (guard); writes tok9
    QKT(9,  5,  0, sA0, sB0, sA1, sB1);   // tail: no issues, drain 5 then 0
#undef QKT

    // ---- write Q f16 into per-wave [64][80] region (aliases toks+low strips) ----
    const int qoff = w * 5120;
#pragma unroll
    for (int mi = 0; mi < 4; ++mi)
#pragma unroll
        for (int ni = 0; ni < 5; ++ni)
#pragma unroll
            for (int r = 0; r < 4; ++r)
                lds[qoff + (mi*16 + lhi*4 + r)*80 + ni*16 + l15] = f2h(acc[mi][ni][r]);
    __builtin_amdgcn_sched_barrier(0);

    const f16x8 zf = {};
    f16x8 PE[5], PO[5];
#define ATT_KK(PC, PN, FB, KK, NKK, DOPF) do { \
    if (DOPF) { \
        _Pragma("unroll") for (int f = 0; f < 5; ++f) \
            (PN)[f] = *(const f16x8*)((FB) + (f * 3 + (NKK)) * 512 + lane * 8); \
    } \
    const int kcol = ((KK) < 2) ? ((KK)*32 + lhi*8) : (64 + (lhi & 1)*8); \
    PRIO1(); \
    _Pragma("unroll") for (int mi = 0; mi < 4; ++mi) { \
        f16x8 aq_ = *(const f16x8*)&lds[qoff + (mi*16 + l15)*80 + kcol]; \
        if ((KK) == 2 && lhi >= 2) aq_ = zf; \
        _Pragma("unroll") for (int ni = 0; ni < 5; ++ni) \
            acc[mi][ni] = __builtin_amdgcn_mfma_f32_16x16x32_f16(aq_, (PC)[ni], acc[mi][ni], 0, 0, 0); \
    } \
    PRIO0(); \
} while (0)

    // ---- S = Q K^T ----
    ZACC();
#pragma unroll
    for (int f = 0; f < 5; ++f)
        PE[f] = *(const f16x8*)(KFb + (f * 3) * 512 + lane * 8);
    ATT_KK(PE, PO, KFb, 0, 1, 1);
    ATT_KK(PO, PE, KFb, 1, 2, 1);
    ATT_KK(PE, PO, KFb, 2, 0, 0);
    __builtin_amdgcn_sched_barrier(0);

    // ---- softmax over s (77 valid), P f16 back into Q/P region ----
    const float sc = 0.11180339887498949f;   // 1/sqrt(80)
#pragma unroll
    for (int mi = 0; mi < 4; ++mi)
#pragma unroll
        for (int r = 0; r < 4; ++r) {
            float v0 = acc[mi][0][r]*sc, v1 = acc[mi][1][r]*sc, v2 = acc[mi][2][r]*sc,
                  v3 = acc[mi][3][r]*sc, v4 = acc[mi][4][r]*sc;
            bool ok4 = l15 < 13;
            float mx = fmaxf(fmaxf(v0, v1), fmaxf(v2, v3));
            if (ok4) mx = fmaxf(mx, v4);
#pragma unroll
            for (int off = 1; off < 16; off <<= 1) mx = fmaxf(mx, __shfl_xor(mx, off, 16));
            float p0 = __expf(v0-mx), p1 = __expf(v1-mx), p2 = __expf(v2-mx), p3 = __expf(v3-mx);
            float p4 = ok4 ? __expf(v4-mx) : 0.f;
            float sm = p0+p1+p2+p3+p4;
#pragma unroll
            for (int off = 1; off < 16; off <<= 1) sm += __shfl_xor(sm, off, 16);
            float inv = 1.f / sm;
            int row = mi*16 + lhi*4 + r;
            lds[qoff + row*80 + 0*16 + l15] = f2h(p0*inv);
            lds[qoff + row*80 + 1*16 + l15] = f2h(p1*inv);
            lds[qoff + row*80 + 2*16 + l15] = f2h(p2*inv);
            lds[qoff + row*80 + 3*16 + l15] = f2h(p3*inv);
            lds[qoff + row*80 + 4*16 + l15] = f2h(p4*inv);
        }
    __builtin_amdgcn_sched_barrier(0);

    // ---- O = P V ----
    ZACC();
#pragma unroll
    for (int f = 0; f < 5; ++f)
        PE[f] = *(const f16x8*)(VFb + (f * 3) * 512 + lane * 8);
    ATT_KK(PE, PO, VFb, 0, 1, 1);
    ATT_KK(PO, PE, VFb, 1, 2, 1);
    ATT_KK(PE, PO, VFb, 2, 0, 0);
#undef ATT_KK

    // issue O-proj B(0) early (ostrip disjoint from live Q/P; stays in flight)
    GLOADB_O(0);
    BARND();                              // Q/P regions dead everywhere

    // ---- ctxall [64][640] swizzled = concat of heads ----
#pragma unroll
    for (int mi = 0; mi < 4; ++mi)
#pragma unroll
        for (int ni = 0; ni < 5; ++ni)
#pragma unroll
            for (int r = 0; r < 4; ++r) {
                int row = mi*16 + lhi*4 + r;
                int col = w*80 + ni*16 + l15;
                int slot = col >> 3;
                int phys = (slot & ~7) | ((slot ^ row) & 7);
                lds[row*640 + phys*8 + (col & 7)] = f2h(acc[mi][ni][r]);
            }
    BARND();                              // ctxall ready (O-B0 still in flight)

    // ---- O projection: counted-vmcnt, 2-slot distance-1 pipeline ----
    ZACC();
#define OH(HX, W) do { GLOADB_O((HX) + 1); WAITVM(W); MFMA_O(HX); } while (0)
    OH(0, 5);  OH(1, 5);  OH(2, 5);  OH(3, 5);  OH(4, 5);
    OH(5, 5);  OH(6, 5);  OH(7, 5);  OH(8, 5);  OH(9, 5);
    OH(10, 5); OH(11, 5); OH(12, 5); OH(13, 5); OH(14, 5);
    OH(15, 5); OH(16, 5); OH(17, 5); OH(18, 5); OH(19, 0);
#undef OH

    // ---- epilogue: f32 out + bias ----
#pragma unroll
    for (int ni = 0; ni < 5; ++ni) {
        int col = w*80 + ni*16 + l15;
        float bvl = bo[col];
#pragma unroll
        for (int mi = 0; mi < 4; ++mi)
#pragma unroll
            for (int r = 0; r < 4; ++r)
                out[(rowbase + mi*16 + lhi*4 + r) * 640 + col] = acc[mi][ni][r] + bvl;
    }
#undef STAGE_LOAD
#undef STAGE_WRITE
#undef GLOADB_Q
#undef GLOADB_O
#undef MFMA_Q
#undef MFMA_O
#undef ZACC
}

extern "C" void kernel_launch(void* const* d_in, const int* in_sizes, int n_in,
                              void* d_out, int out_size, void* d_ws, size_t ws_size,
                              hipStream_t stream) {
    (void)in_sizes; (void)n_in; (void)out_size; (void)ws_size;
    const float* tokens  = (const float*)d_in[0];
    const float* context = (const float*)d_in[1];
    const float* Wq = (const float*)d_in[2];
    const float* Wk = (const float*)d_in[3];
    const float* Wv = (const float*)d_in[4];
    const float* Wo = (const float*)d_in[5];
    const float* bo = (const float*)d_in[6];
    float* out = (float*)d_out;

    ushort* ws   = (ushort*)d_ws;
    ushort* ctx16 = ws;                                   // 616*768
    ushort* WkvT = ctx16 + (size_t)616 * 768;             // 1280*768
    ushort* KVb  = WkvT + (size_t)1280 * 768;             // 616*1280
    ushort* WqF  = KVb  + (size_t)616 * 1280;             // 640*640
    ushort* WoF  = WqF  + (size_t)640 * 640;              // 640*640
    ushort* KF   = WoF  + (size_t)640 * 640;              // 61440*8
    ushort* VF   = KF   + (size_t)61440 * 8;              // 61440*8

    cvt_kernel<<<462, 256, 0, stream>>>(context, ctx16, 616 * 768 / 4);
    transpose_cvt2<<<dim3(20, 24, 2), dim3(32, 8), 0, stream>>>(Wk, Wv, WkvT);
    pack_wfrag2<<<dim3(200, 2), 256, 0, stream>>>(Wq, Wo, WqF, WoF);
    gemm_bt<1, 0><<<dim3(5, 10), 256, 0, stream>>>(ctx16, WkvT, KVb, nullptr, 616, 1280, 768);
    pack_kvfrag<<<240, 256, 0, stream>>>(KVb, KF, VF);
    fused_attn<<<dim3(64, 8), 512, 0, stream>>>(tokens, WqF, KF, VF, WoF, bo, out);
}